// Round 1
// baseline (131.606 us; speedup 1.0000x reference)
//
#include <hip/hip_runtime.h>

// Problem constants (from reference): B=256, N=25, C=256, H/2=128.
// Telescoping identity: edge_feat[b,i,j,:] = src[b,j,:] - src[b,i,:]
//  => u = src @ W1^T  ([B,25,128]),  out[b,i,j] = sum_h prelu(u_j - u_i)*W2[h]
#define NJ   25
#define CIN  256
#define HH   128
#define US   132   // padded LDS stride (multiple of 4 for float4 alignment)

__global__ __launch_bounds__(256) void fused_edge_mlp_kernel(
    const float* __restrict__ src,   // [B, 25, 256]
    const float* __restrict__ W1,    // [128, 256]
    const float* __restrict__ Aarr,  // [1] PReLU alpha
    const float* __restrict__ W2,    // [128]
    float* __restrict__ out)         // [B, 25, 25]
{
    __shared__ float u_s[NJ * US];   // u[b] : 25 x 128, stride 132

    const int b    = blockIdx.x;
    const int t    = threadIdx.x;
    const int h    = t & (HH - 1);   // output feature 0..127
    const int half = t >> 7;         // c-range half: 0 or 1

    // ---------------- Stage 1: u[n][h] = sum_c src[b,n,c] * W1[h,c] ----------------
    // Each thread accumulates 25 outputs (all n) for its (h, c-half).
    const float4* __restrict__ s4  =
        reinterpret_cast<const float4*>(src) + (long)b * (NJ * CIN / 4);
    const float4* __restrict__ w1v =
        reinterpret_cast<const float4*>(W1) + h * (CIN / 4);

    float acc[NJ];
    #pragma unroll
    for (int n = 0; n < NJ; ++n) acc[n] = 0.f;

    const int cbase = half * 32;     // in float4 units
    for (int c4 = 0; c4 < 32; ++c4) {
        const float4 w4 = w1v[cbase + c4];
        const int off = cbase + c4;
        #pragma unroll
        for (int n = 0; n < NJ; ++n) {
            // wave-uniform address -> scalar loads feed the VALU
            const float4 sv = s4[n * (CIN / 4) + off];
            acc[n] += sv.x * w4.x + sv.y * w4.y + sv.z * w4.z + sv.w * w4.w;
        }
    }

    // Combine the two c-halves through LDS.
    if (half) {
        #pragma unroll
        for (int n = 0; n < NJ; ++n) u_s[n * US + h] = acc[n];
    }
    __syncthreads();
    if (!half) {
        #pragma unroll
        for (int n = 0; n < NJ; ++n) u_s[n * US + h] += acc[n];
    }
    __syncthreads();

    // ---------------- Stage 2: out[b,i,j] = sum_h prelu(u_j[h]-u_i[h]) * W2[h] ----
    const float alpha = Aarr[0];
    const float4* __restrict__ w2v = reinterpret_cast<const float4*>(W2);
    float* __restrict__ outb = out + (long)b * (NJ * NJ);

    for (int p = t; p < NJ * NJ; p += 256) {
        const int i = p / NJ;
        const int j = p - i * NJ;
        const float* __restrict__ uj = u_s + j * US;
        const float* __restrict__ ui = u_s + i * US;
        float accP = 0.f, accN = 0.f;
        #pragma unroll 8
        for (int h4 = 0; h4 < HH / 4; ++h4) {
            const float4 a4  = *reinterpret_cast<const float4*>(uj + 4 * h4);
            const float4 b4  = *reinterpret_cast<const float4*>(ui + 4 * h4);
            const float4 w24 = w2v[h4];   // wave-uniform -> scalar load
            float d;
            d = a4.x - b4.x; accP = fmaf(w24.x, fmaxf(d, 0.f), accP); accN = fmaf(w24.x, fminf(d, 0.f), accN);
            d = a4.y - b4.y; accP = fmaf(w24.y, fmaxf(d, 0.f), accP); accN = fmaf(w24.y, fminf(d, 0.f), accN);
            d = a4.z - b4.z; accP = fmaf(w24.z, fmaxf(d, 0.f), accP); accN = fmaf(w24.z, fminf(d, 0.f), accN);
            d = a4.w - b4.w; accP = fmaf(w24.w, fmaxf(d, 0.f), accP); accN = fmaf(w24.w, fminf(d, 0.f), accN);
        }
        outb[p] = accP + alpha * accN;
    }
}

extern "C" void kernel_launch(void* const* d_in, const int* in_sizes, int n_in,
                              void* d_out, int out_size, void* d_ws, size_t ws_size,
                              hipStream_t stream) {
    // inputs: 0=src [B,25,256] f32, 1=heads, 2=ends, 3=pair_ids (unused: path
    // sums telescope), 4=W1 [128,256] f32, 5=alpha [1] f32, 6=W2 [1,128] f32
    const float* src   = (const float*)d_in[0];
    const float* W1    = (const float*)d_in[4];
    const float* alpha = (const float*)d_in[5];
    const float* W2    = (const float*)d_in[6];
    float* out = (float*)d_out;

    const int B = in_sizes[0] / (NJ * CIN);   // 256
    fused_edge_mlp_kernel<<<B, 256, 0, stream>>>(src, W1, alpha, W2, out);
}

// Round 2
// 75.726 us; speedup vs baseline: 1.7379x; 1.7379x over previous
//
#include <hip/hip_runtime.h>

// B=256, N=25, C=256, H/2=128.  Telescoping: edge_feat[b,i,j,:] = src[b,j] - src[b,i]
//  => u = src @ W1^T ([25,128] per b, via bf16 MFMA), out[i,j] = sum_h prelu(u_j-u_i)*W2[h]
#define NJ    25
#define CIN   256
#define HH    128
#define AS    264          // a_s row stride in shorts (528B = 132 banks, 16B aligned)

typedef __attribute__((ext_vector_type(8))) short short8;
typedef __attribute__((ext_vector_type(4))) float f32x4;

__device__ __forceinline__ unsigned short f2bf(float f) {
    union { float f; unsigned u; } v; v.f = f;
    unsigned r = v.u + 0x7FFF + ((v.u >> 16) & 1);   // round-to-nearest-even
    return (unsigned short)(r >> 16);
}
__device__ __forceinline__ float bf2f(short s) {
    union { unsigned u; float f; } v;
    v.u = ((unsigned)(unsigned short)s) << 16;
    return v.f;
}

__global__ __launch_bounds__(512) void fused_edge_mlp_mfma(
    const float* __restrict__ src,   // [B,25,256]
    const float* __restrict__ W1,    // [128,256]
    const float* __restrict__ Aarr,  // [1] alpha
    const float* __restrict__ W2,    // [128]
    float* __restrict__ out)         // [B,25,25]
{
    __shared__ short a_s[32 * AS];          // src[b] as bf16, rows 25..31 zeroed (33.8 KB)
    __shared__ short u8s[16 * 26 * 8];      // u as bf16: chunk h8 (8 h) x joint j (6.7 KB)

    const int b = blockIdx.x;
    const int t = threadIdx.x;

    // ---------------- Phase 0: stage src[b] -> LDS bf16; zero pad rows -------------
    {
        unsigned* au = (unsigned*)a_s;
        for (int i = (25 * AS) / 2 + t; i < (32 * AS) / 2; i += 512) au[i] = 0u;
        const float4* s4 = reinterpret_cast<const float4*>(src) + (long)b * (NJ * CIN / 4);
        for (int idx = t; idx < NJ * CIN / 4; idx += 512) {
            int n  = idx >> 6;          // 64 float4 per row
            int k4 = idx & 63;
            float4 v = s4[idx];
            unsigned lo = (unsigned)f2bf(v.x) | ((unsigned)f2bf(v.y) << 16);
            unsigned hi = (unsigned)f2bf(v.z) | ((unsigned)f2bf(v.w) << 16);
            uint2* dst = (uint2*)&a_s[n * AS + k4 * 4];
            *dst = make_uint2(lo, hi);
        }
    }
    __syncthreads();

    // ---------------- Phase 1: u = src_bf16 @ W1_bf16^T via MFMA -------------------
    // wave w owns N-tile (16 h columns); loops M-tiles {0,1}; K = 8 tiles of 32.
    {
        const int w    = t >> 6;         // 0..7 = Ntile
        const int lane = t & 63;
        const int ln15 = lane & 15;
        const int quad = lane >> 4;
        const int hcol = w * 16 + ln15;

        // B fragments direct from global W1 (L2-resident), fp32 -> bf16
        short8 bfrag[8];
        const float* w1row = W1 + hcol * CIN;
        #pragma unroll
        for (int kt = 0; kt < 8; ++kt) {
            const float* p = w1row + kt * 32 + quad * 8;
            float4 x = *reinterpret_cast<const float4*>(p);
            float4 y = *reinterpret_cast<const float4*>(p + 4);
            short8 bf;
            bf[0] = (short)f2bf(x.x); bf[1] = (short)f2bf(x.y);
            bf[2] = (short)f2bf(x.z); bf[3] = (short)f2bf(x.w);
            bf[4] = (short)f2bf(y.x); bf[5] = (short)f2bf(y.y);
            bf[6] = (short)f2bf(y.z); bf[7] = (short)f2bf(y.w);
            bfrag[kt] = bf;
        }

        f32x4 acc0 = {0.f, 0.f, 0.f, 0.f};
        f32x4 acc1 = {0.f, 0.f, 0.f, 0.f};
        #pragma unroll
        for (int kt = 0; kt < 8; ++kt) {
            const int ko = kt * 32 + quad * 8;
            short8 a0 = *reinterpret_cast<const short8*>(&a_s[(ln15)      * AS + ko]);
            short8 a1 = *reinterpret_cast<const short8*>(&a_s[(16 + ln15) * AS + ko]);
            acc0 = __builtin_amdgcn_mfma_f32_16x16x32_bf16(a0, bfrag[kt], acc0, 0, 0, 0);
            acc1 = __builtin_amdgcn_mfma_f32_16x16x32_bf16(a1, bfrag[kt], acc1, 0, 0, 0);
        }

        // D layout: col(h)=lane&15, row(m)=quad*4+reg.  Write u -> LDS bf16,
        // layout u8s[(h>>3)*26 + m)*8 + (h&7)] so phase-2 reads are j-consecutive b128.
        const int h8  = hcol >> 3;
        const int hlo = hcol & 7;
        #pragma unroll
        for (int r = 0; r < 4; ++r) {
            int m0 = quad * 4 + r;
            if (m0 < NJ) u8s[(h8 * 26 + m0) * 8 + hlo] = (short)f2bf(acc0[r]);
            int m1 = 16 + quad * 4 + r;
            if (m1 < NJ) u8s[(h8 * 26 + m1) * 8 + hlo] = (short)f2bf(acc1[r]);
        }
    }
    __syncthreads();

    // ---------------- Phase 2: out[i,j] = accP + alpha*(accS - accP) ----------------
    //   accS = sum_h w2*d   accP = sum_h w2*max(d,0)   (accS-accP = sum w2*min(d,0))
    const float alpha = Aarr[0];
    float* outb = out + (long)b * (NJ * NJ);

    for (int p = t; p < NJ * NJ; p += 512) {
        int i = p / NJ;
        int j = p - i * NJ;
        float accS = 0.f, accP = 0.f;
        #pragma unroll 4
        for (int h8 = 0; h8 < 16; ++h8) {
            short8 uj = *reinterpret_cast<const short8*>(&u8s[(h8 * 26 + j) * 8]);
            short8 ui = *reinterpret_cast<const short8*>(&u8s[(h8 * 26 + i) * 8]);
            const float* w2p = W2 + h8 * 8;    // wave-uniform -> scalar loads
            #pragma unroll
            for (int q = 0; q < 8; ++q) {
                float d = bf2f(uj[q]) - bf2f(ui[q]);
                float w = w2p[q];
                accS = fmaf(w, d, accS);
                accP = fmaf(w, fmaxf(d, 0.f), accP);
            }
        }
        outb[p] = accP + alpha * (accS - accP);
    }
}

extern "C" void kernel_launch(void* const* d_in, const int* in_sizes, int n_in,
                              void* d_out, int out_size, void* d_ws, size_t ws_size,
                              hipStream_t stream) {
    // inputs: 0=src, 1=heads, 2=ends, 3=pair_ids (unused: telescoping), 4=W1, 5=alpha, 6=W2
    const float* src   = (const float*)d_in[0];
    const float* W1    = (const float*)d_in[4];
    const float* alpha = (const float*)d_in[5];
    const float* W2    = (const float*)d_in[6];
    float* out = (float*)d_out;

    const int B = in_sizes[0] / (NJ * CIN);   // 256
    fused_edge_mlp_mfma<<<B, 512, 0, stream>>>(src, W1, alpha, W2, out);
}